// Round 3
// baseline (64.773 us; speedup 1.0000x reference)
//
#include <hip/hip_runtime.h>

namespace {

constexpr int NQ   = 10;    // qubits
constexpr int DIM  = 1024;  // 2^10 amplitudes
constexpr int NL   = 3;     // layers
constexpr int FEAT = 20;    // input features per sample
constexpr int S    = 32;    // batch

// One block per sample. State vector (1024 complex) lives in LDS.
// Each of the 512 threads owns one disjoint (i0, i1) pair per single-qubit
// gate, so gate updates are race-free with a single barrier per gate.
//
// Output layout (fp32): real plane at [s*1024 + j]; if the output buffer is
// the full 65536 floats, imag plane at [32768 + s*1024 + j] (planar re/im).
__global__ __launch_bounds__(512) void qsim(const float* __restrict__ X,
                                            const float* __restrict__ W,
                                            const float* __restrict__ Bb,
                                            float* __restrict__ out,
                                            int write_imag)
{
    const int s   = blockIdx.x;
    const int tid = threadIdx.x;

    __shared__ float2 st[DIM];      // state amplitudes (re, im)
    __shared__ float2 gm[NQ][4];    // per-qubit gate: m00, m01, m10, m11

    // |0...0> initial state
    st[tid]       = make_float2(0.f, 0.f);
    st[tid + 512] = make_float2(0.f, 0.f);
    if (tid == 0) st[0] = make_float2(1.f, 0.f);

    // Ring-CNOT permutation gather indices: new[j] = old[r(j)].
    // Reference composes total = total[cnot_perm(c,t)] over pairs
    // (0,1)...(8,9),(9,0); total[j] = P01(P12(...(P89(P90(j))))), so apply
    // P90 first, then c=8..0. Qubit q sits at bit (9-q) (qubit 0 = MSB).
    // (Verified element-wise against the reference composition for n=2 and 3.)
    int r0 = tid, r1 = tid + 512;
    if (r0 & 1) r0 ^= 1 << 9;       // pair (9,0): ctrl bit0 -> flip bit9
    if (r1 & 1) r1 ^= 1 << 9;
#pragma unroll
    for (int c = 8; c >= 0; --c) {  // pair (c,c+1): ctrl bit(9-c) -> flip bit(8-c)
        if ((r0 >> (9 - c)) & 1) r0 ^= 1 << (8 - c);
        if ((r1 >> (9 - c)) & 1) r1 ^= 1 << (8 - c);
    }

    float2 v0 = make_float2(0.f, 0.f), v1 = v0;

    for (int l = 0; l < NL; ++l) {
        // --- build the 10 Rot(phi, theta, omega) matrices for this layer ---
        if (tid < NQ) {
            const int base = l * 30 + tid * 3;
            const float phi   = X[s * FEAT + (base    ) % FEAT] * W[base    ] + Bb[base    ];
            const float theta = X[s * FEAT + (base + 1) % FEAT] * W[base + 1] + Bb[base + 1];
            const float omega = X[s * FEAT + (base + 2) % FEAT] * W[base + 2] + Bb[base + 2];
            float sn, ct;  sincosf(0.5f * theta,          &sn, &ct);
            float sp, cp;  sincosf(0.5f * (phi + omega),  &sp, &cp);
            float sm, cm;  sincosf(0.5f * (phi - omega),  &sm, &cm);
            gm[tid][0] = make_float2( cp * ct, -sp * ct);  // e^{-i(phi+omega)/2} cos
            gm[tid][1] = make_float2(-cm * sn, -sm * sn);  // -e^{+i(phi-omega)/2} sin
            gm[tid][2] = make_float2( cm * sn, -sm * sn);  // e^{-i(phi-omega)/2} sin
            gm[tid][3] = make_float2( cp * ct,  sp * ct);  // e^{+i(phi+omega)/2} cos
        }
        __syncthreads();

        // --- apply the 10 single-qubit gates (Kronecker factorization) ---
#pragma unroll
        for (int q = 0; q < NQ; ++q) {
            const int b   = 9 - q;                       // bit position of qubit q
            const int low = tid & ((1 << b) - 1);
            const int i0  = ((tid >> b) << (b + 1)) | low;
            const int i1  = i0 | (1 << b);

            const float2 a   = st[i0];
            const float2 c   = st[i1];
            const float2 m00 = gm[q][0], m01 = gm[q][1];
            const float2 m10 = gm[q][2], m11 = gm[q][3];

            float2 n0, n1;
            n0.x = m00.x * a.x - m00.y * a.y + m01.x * c.x - m01.y * c.y;
            n0.y = m00.x * a.y + m00.y * a.x + m01.x * c.y + m01.y * c.x;
            n1.x = m10.x * a.x - m10.y * a.y + m11.x * c.x - m11.y * c.y;
            n1.y = m10.x * a.y + m10.y * a.x + m11.x * c.y + m11.y * c.x;

            st[i0] = n0;   // this thread owns the pair: no intra-gate race
            st[i1] = n1;
            __syncthreads();
        }

        // --- ring-CNOT permutation: gather, barrier, scatter back ---
        v0 = st[r0];
        v1 = st[r1];
        __syncthreads();
        st[tid]       = v0;
        st[tid + 512] = v1;
        __syncthreads();
    }

    // Planar output: real plane first, imag plane (if present) second.
    out[s * DIM + tid]       = v0.x;
    out[s * DIM + tid + 512] = v1.x;
    if (write_imag) {
        out[S * DIM + s * DIM + tid]       = v0.y;
        out[S * DIM + s * DIM + tid + 512] = v1.y;
    }
}

} // namespace

extern "C" void kernel_launch(void* const* d_in, const int* in_sizes, int n_in,
                              void* d_out, int out_size, void* d_ws, size_t ws_size,
                              hipStream_t stream) {
    const float* X = (const float*)d_in[0];   // (32, 20) fp32
    const float* W = (const float*)d_in[1];   // (3, 10, 3) fp32
    const float* B = (const float*)d_in[2];   // (3, 10, 3) fp32
    (void)in_sizes; (void)n_in; (void)d_ws; (void)ws_size;
    const int write_imag = (out_size >= 2 * S * DIM) ? 1 : 0;
    qsim<<<S, 512, 0, stream>>>(X, W, B, (float*)d_out, write_imag);
}